// Round 12
// baseline (194.843 us; speedup 1.0000x reference)
//
#include <hip/hip_runtime.h>

// Problem constants (B=8, C=512, H=W=64, K=19 classes)
#define NCLS   19
#define NB     8
#define NC     512
#define NHW    4096      // 64*64
#define EPSM   1e-6f     // mean denominator eps
#define EPSC   1e-8f     // cosine eps

// Workspace layout (bytes)
#define OFF_LABELS   0u          // int32 [NB*NHW]
#define OFF_COUNTS   131072u     // float [NB*NCLS] ([b][k])
#define OFF_SUMS_S   132096u     // float [NB][NCLS][NC]  (means S after k_means, in place)
#define OFF_SUMS_T   443392u     // float [NB][NCLS][NC]
#define OFF_NORM_S   754688u     // float [NB*NCLS]
#define OFF_NORM_T   755712u     // float [NB*NCLS]
// (part[] region no longer used — k_dots/k_final fused in round 12)

// ---------------------------------------------------------------------------
// Wave-64 sum via DPP (VALU pipe only, no LDS). Result valid in lane 63.
template<int CTRL>
__device__ __forceinline__ float dpp_add(float x) {
    int y = __builtin_amdgcn_update_dpp(0, __float_as_int(x), CTRL, 0xf, 0xf, false);
    return x + __int_as_float(y);
}
__device__ __forceinline__ float wave64_sum(float x) {
    x = dpp_add<0x111>(x);   // row_shr:1
    x = dpp_add<0x112>(x);   // row_shr:2
    x = dpp_add<0x114>(x);   // row_shr:4
    x = dpp_add<0x118>(x);   // row_shr:8  -> lane15 of each row16 has row sum
    x = dpp_add<0x142>(x);   // row_bcast:15 -> lane31/63 have half sums
    x = dpp_add<0x143>(x);   // row_bcast:31 -> lane63 has total
    return x;
}

// ---------------------------------------------------------------------------
// Kernel 1: nearest-resize labels (512x512 -> 64x64) + per-batch class counts.
// One block per batch; counts written DIRECTLY (no global atomics) -> the
// counts memset dispatch is deleted (round 12: dispatch-count reduction).
__global__ __launch_bounds__(256) void k_labels(const int* __restrict__ target,
                                                int* __restrict__ labels,
                                                float* __restrict__ counts) {
    __shared__ int hist[NCLS];
    const int b = blockIdx.x;
    const int t = threadIdx.x;
    if (t < NCLS) hist[t] = 0;
    __syncthreads();
    const int* tb = target + (size_t)b * 512 * 512;
    #pragma unroll
    for (int i = 0; i < 16; ++i) {
        int n = t + i * 256;
        int y = n >> 6, x = n & 63;
        int l = tb[(y * 8) * 512 + x * 8];   // in_idx = floor(out_idx*512/64)
        labels[b * NHW + n] = l;
        if (l >= 0 && l < NCLS) atomicAdd(&hist[l], 1);
    }
    __syncthreads();
    if (t < NCLS) counts[b * NCLS + t] = (float)hist[t];
}

// ---------------------------------------------------------------------------
// Kernel 2: per-class channel sums, LDS column-private float2 accumulator
// (r11 version, unchanged — best measured: 42.7 us).
//
// ALGORITHM HISTORY: r0-r4/r6 mask-accumulate O(19)/elem ~57 us VALU floor;
// r5 LDS atomics 174 us (per-lane serialization — poison); r7 column
// scatter 51; r8 float2 pack 48.6; r10/r11 prefetch attempts — compiler
// sinks the loads (VGPR pinned at 52 both times; sched_barrier helped -4 us
// anyway). 42.7 us, all pipes <25%: accepted for now; round 12 targets the
// ~90 us of dispatch overhead instead (total - k_sums ~= 146 us constant
// across ALL rounds while k_dots <= 42 us by top-5 cutoff bound).
__global__ __launch_bounds__(256) void k_sums(const float* __restrict__ fS,
                                              const float* __restrict__ fT,
                                              const int* __restrict__ labels,
                                              float* __restrict__ sumsS,
                                              float* __restrict__ sumsT) {
    __shared__ float2 acc[NCLS * 256];   // 38912 B
    const int t   = threadIdx.x;
    const int blk = blockIdx.x;          // 0..4095
    const int b   = blk >> 9;            // 512 channels per batch
    const int c   = blk & (NC - 1);

    const int4*   lab4 = (const int4*)(labels + b * NHW);
    const float4* pS   = (const float4*)(fS + ((size_t)(b * NC) + c) * NHW);
    const float4* pT   = (const float4*)(fT + ((size_t)(b * NC) + c) * NHW);

    int4 lab[4]; float4 vS[4]; float4 vT[4];
    #pragma unroll
    for (int j = 0; j < 4; ++j) {
        lab[j] = lab4[t + (j << 8)];
        vS[j]  = pS[t + (j << 8)];
        vT[j]  = pT[t + (j << 8)];
    }
    __builtin_amdgcn_sched_barrier(0);

    {   // zero LDS, vectorized: 19*256*8B / 16B = 2432 float4
        float4* av = (float4*)acc;
        const float4 z = make_float4(0.f, 0.f, 0.f, 0.f);
        for (int i = t; i < NCLS * 128; i += 256) av[i] = z;
    }
    __syncthreads();

    float2* a0 = acc + t;                // element k at a0[k<<8]

    #pragma unroll
    for (int j = 0; j < 4; ++j) {        // fully unrolled: static reg indices
        const int4   l = lab[j];
        const float4 s = vS[j];
        const float4 u = vT[j];
        if ((unsigned)l.x < NCLS) { float2 v = a0[l.x << 8]; v.x += s.x; v.y += u.x; a0[l.x << 8] = v; }
        if ((unsigned)l.y < NCLS) { float2 v = a0[l.y << 8]; v.x += s.y; v.y += u.y; a0[l.y << 8] = v; }
        if ((unsigned)l.z < NCLS) { float2 v = a0[l.z << 8]; v.x += s.z; v.y += u.z; a0[l.z << 8] = v; }
        if ((unsigned)l.w < NCLS) { float2 v = a0[l.w << 8]; v.x += s.w; v.y += u.w; a0[l.w << 8] = v; }
    }
    __syncthreads();

    // Reduce 19 float2-rows of 256; rows round-robin over the 4 waves.
    const int w = t >> 6, lane = t & 63;
    for (int r = w; r < NCLS; r += 4) {
        const float2* row = acc + r * 256;
        const float2 p0 = row[lane], p1 = row[lane + 64];
        const float2 p2 = row[lane + 128], p3 = row[lane + 192];
        float sx = (p0.x + p1.x) + (p2.x + p3.x);
        float sy = (p0.y + p1.y) + (p2.y + p3.y);
        sx = wave64_sum(sx);
        sy = wave64_sum(sy);
        if (lane == 63) {
            sumsS[((size_t)(b * NCLS + r)) * NC + c] = sx;
            sumsT[((size_t)(b * NCLS + r)) * NC + c] = sy;
        }
    }
}

// ---------------------------------------------------------------------------
// Kernel 3: means = sums/(count+eps) in place + per-(b,k) center norms.
// Also zeroes d_out (stream-ordered before k_dots' atomicAdds) -> the
// d_out memset dispatch is deleted.
__global__ __launch_bounds__(64) void k_means(float* __restrict__ sumsS,
                                              float* __restrict__ sumsT,
                                              const float* __restrict__ counts,
                                              float* __restrict__ normS,
                                              float* __restrict__ normT,
                                              float* __restrict__ out) {
    const int bk = blockIdx.x;
    const int t = threadIdx.x;
    if (bk == 0 && t == 0) *out = 0.f;
    const float inv = 1.f / (counts[bk] + EPSM);
    float* rS = sumsS + (size_t)bk * NC;
    float* rT = sumsT + (size_t)bk * NC;
    float aS = 0.f, aT = 0.f;
    #pragma unroll
    for (int i = 0; i < NC / 64; ++i) {
        float mS = rS[t + i * 64] * inv; rS[t + i * 64] = mS; aS += mS * mS;
        float mT = rT[t + i * 64] * inv; rT[t + i * 64] = mT; aT += mT * mT;
    }
    aS = wave64_sum(aS);
    aT = wave64_sum(aT);
    if (t == 63) { normS[bk] = sqrtf(aS); normT[bk] = sqrtf(aT); }
}

// ---------------------------------------------------------------------------
// Kernel 4 (FUSED k_dots + k_final, round 12): per-pixel dot/norm over ALL
// 512 channels in one block, cosine + MSE inline, one atomicAdd per block.
// Eliminates the part[] 8 MB round-trip and the k_final dispatch.
//
// Block = (b, 64-pixel tile); 512 blocks x 256 thr. Wave w owns channels
// [128w, 128w+128) in 2 stage-rounds of 64; lane = pixel (coalesced 256 B
// feature loads). Means staged as float2 [w][k][65]: gather addr in float2
// units = (w*19+k)*65+ci -> bank = (2k+K)%32 -> distinct k differ unless
// k' = k+16 (<=2-way aliasing = free, m136). Per-pixel 4-wave partials
// combined via LDS float4; wave 0 finishes cosine+MSE.
// LDS: 4*19*65*8 + 4*64*16 = 43,616 B -> 3 blocks/CU.
__global__ __launch_bounds__(256) void k_dots(const float* __restrict__ fS,
                                              const float* __restrict__ fT,
                                              const float* __restrict__ meansS,
                                              const float* __restrict__ meansT,
                                              const int* __restrict__ labels,
                                              const float* __restrict__ normS,
                                              const float* __restrict__ normT,
                                              float* __restrict__ out) {
    __shared__ float2 mST[4 * NCLS * 65];   // [w][k][ci] (.x=S,.y=T)
    __shared__ float4 red[4 * 64];          // [w][px]: dS,nS,dT,nT
    const int t    = threadIdx.x;
    const int w    = t >> 6, px = t & 63;
    const int blk  = blockIdx.x;            // 0..511
    const int b    = blk >> 6;              // 64 tiles per batch
    const int tile = blk & 63;
    const int n    = tile * 64 + px;

    const int l  = labels[b * NHW + n];
    const int lc = (l >= 0 && l < NCLS) ? l : 0;

    float dS = 0.f, nS = 0.f, dT = 0.f, nT = 0.f;
    #pragma unroll
    for (int r = 0; r < 2; ++r) {
        __syncthreads();                    // protect prior round's reads
        for (int i = t; i < 4 * NCLS * 64; i += 256) {
            const int ww  = i / (NCLS * 64);
            const int rem = i - ww * (NCLS * 64);
            const int k   = rem >> 6, ci = rem & 63;
            const int c   = ww * 128 + r * 64 + ci;
            mST[(ww * NCLS + k) * 65 + ci] = make_float2(
                meansS[((size_t)(b * NCLS + k)) * NC + c],
                meansT[((size_t)(b * NCLS + k)) * NC + c]);
        }
        __syncthreads();
        const size_t base = ((size_t)(b * NC) + w * 128 + r * 64) * NHW + tile * 64 + px;
        const float* pS = fS + base;
        const float* pT = fT + base;
        const float2* m0 = mST + (w * NCLS + lc) * 65;
        #pragma unroll 8
        for (int ci = 0; ci < 64; ++ci) {
            const float vS = pS[(size_t)ci * NHW];
            const float vT = pT[(size_t)ci * NHW];
            const float2 m = m0[ci];
            dS += vS * m.x; nS += vS * vS;
            dT += vT * m.y; nT += vT * vT;
        }
    }
    red[w * 64 + px] = make_float4(dS, nS, dT, nT);
    __syncthreads();

    if (w == 0) {
        const float4 a0 = red[px],       a1 = red[64 + px];
        const float4 a2 = red[128 + px], a3 = red[192 + px];
        const float DS = (a0.x + a1.x) + (a2.x + a3.x);
        const float NS = (a0.y + a1.y) + (a2.y + a3.y);
        const float DT = (a0.z + a1.z) + (a2.z + a3.z);
        const float NT = (a0.w + a1.w) + (a2.w + a3.w);
        float val = 0.f;
        if (l >= 0 && l < NCLS) {
            const float cS = DS / (fmaxf(sqrtf(NS), EPSC) * fmaxf(normS[b * NCLS + l], EPSC));
            const float cT = DT / (fmaxf(sqrtf(NT), EPSC) * fmaxf(normT[b * NCLS + l], EPSC));
            const float d = cS - cT;
            val = d * d;
        }
        val = wave64_sum(val);
        if (px == 63) atomicAdd(out, val * (1.f / (NB * NHW)));
    }
}

// ---------------------------------------------------------------------------
extern "C" void kernel_launch(void* const* d_in, const int* in_sizes, int n_in,
                              void* d_out, int out_size, void* d_ws, size_t ws_size,
                              hipStream_t stream) {
    (void)in_sizes; (void)n_in; (void)out_size; (void)ws_size;
    const float* fS     = (const float*)d_in[0];
    const float* fT     = (const float*)d_in[1];
    const int*   target = (const int*)d_in[2];

    char* ws = (char*)d_ws;
    int*   labels = (int*)  (ws + OFF_LABELS);
    float* counts = (float*)(ws + OFF_COUNTS);
    float* sumsS  = (float*)(ws + OFF_SUMS_S);   // means after k_means (in place)
    float* sumsT  = (float*)(ws + OFF_SUMS_T);
    float* normS  = (float*)(ws + OFF_NORM_S);
    float* normT  = (float*)(ws + OFF_NORM_T);

    // 4 dispatches total (was 7: 2 memsets folded in, k_final fused away).
    k_labels<<<NB, 256, 0, stream>>>(target, labels, counts);
    k_sums  <<<NB * NC, 256, 0, stream>>>(fS, fT, labels, sumsS, sumsT);
    k_means <<<NB * NCLS, 64, 0, stream>>>(sumsS, sumsT, counts, normS, normT,
                                           (float*)d_out);
    k_dots  <<<NB * 64, 256, 0, stream>>>(fS, fT, sumsS, sumsT, labels,
                                          normS, normT, (float*)d_out);
}

// Round 13
// 190.254 us; speedup vs baseline: 1.0241x; 1.0241x over previous
//
#include <hip/hip_runtime.h>

// Problem constants (B=8, C=512, H=W=64, K=19 classes)
#define NCLS   19
#define NB     8
#define NC     512
#define NHW    4096      // 64*64
#define EPSM   1e-6f     // mean denominator eps
#define EPSC   1e-8f     // cosine eps
#define LBLK   8         // k_labels blocks per batch

// Workspace layout (bytes)
#define OFF_LABELS   0u          // int32 [NB*NHW]
#define OFF_SUMS_S   132096u     // float [NB][NCLS][NC]  (means S after k_means, in place)
#define OFF_SUMS_T   443392u     // float [NB][NCLS][NC]
#define OFF_NORM_S   754688u     // float [NB*NCLS]
#define OFF_NORM_T   755712u     // float [NB*NCLS]
#define OFF_COUNTSP  756736u     // float [NB*LBLK][NCLS] label-count partials (old part[] region)

// ---------------------------------------------------------------------------
// Wave-64 sum via DPP (VALU pipe only, no LDS). Result valid in lane 63.
template<int CTRL>
__device__ __forceinline__ float dpp_add(float x) {
    int y = __builtin_amdgcn_update_dpp(0, __float_as_int(x), CTRL, 0xf, 0xf, false);
    return x + __int_as_float(y);
}
__device__ __forceinline__ float wave64_sum(float x) {
    x = dpp_add<0x111>(x);   // row_shr:1
    x = dpp_add<0x112>(x);   // row_shr:2
    x = dpp_add<0x114>(x);   // row_shr:4
    x = dpp_add<0x118>(x);   // row_shr:8  -> lane15 of each row16 has row sum
    x = dpp_add<0x142>(x);   // row_bcast:15 -> lane31/63 have half sums
    x = dpp_add<0x143>(x);   // row_bcast:31 -> lane63 has total
    return x;
}

// Async global->LDS DMA, 16 B/lane (no VGPR destination: MLP without regs).
// LDS base must be wave-uniform; HW writes base + lane*16.
__device__ __forceinline__ void g2lds16(const float* g, float* l) {
    __builtin_amdgcn_global_load_lds(
        (const __attribute__((address_space(1))) float*)g,
        (__attribute__((address_space(3))) float*)l, 16, 0, 0);
}

// ---------------------------------------------------------------------------
// Kernel 1: nearest-resize labels + per-slice class-count partials.
// 64 blocks (r12's revert to 8 blocks re-serialized the latency-bound gather
// and regressed ~10 us — restored). Race-free: block (b,part) writes its own
// countsP row; k_means sums the 8 slices. No memset needed.
__global__ __launch_bounds__(256) void k_labels(const int* __restrict__ target,
                                                int* __restrict__ labels,
                                                float* __restrict__ countsP) {
    __shared__ int hist[NCLS];
    const int blk  = blockIdx.x;         // 0..63
    const int b    = blk >> 3;
    const int part = blk & (LBLK - 1);   // 512-pixel slice
    const int t = threadIdx.x;
    if (t < NCLS) hist[t] = 0;
    __syncthreads();
    const int* tb = target + (size_t)b * 512 * 512;
    #pragma unroll
    for (int i = 0; i < 2; ++i) {
        int n = part * 512 + t + i * 256;
        int y = n >> 6, x = n & 63;
        int l = tb[(y * 8) * 512 + x * 8];   // in_idx = floor(out_idx*512/64)
        labels[b * NHW + n] = l;
        if (l >= 0 && l < NCLS) atomicAdd(&hist[l], 1);
    }
    __syncthreads();
    if (t < NCLS) countsP[(size_t)blk * NCLS + t] = (float)hist[t];
}

// ---------------------------------------------------------------------------
// Kernel 2: per-class channel sums — ASYNC-DMA staged (this round's lever).
//
// ALGORITHM HISTORY: r0-r4/r6 mask O(19)/elem ~57 us; r5 LDS atomics 174 us
// (per-lane serialization — poison); r7 column scatter 51; r8 float2 pack
// 48.6; r10/r11 register prefetch DEFEATED TWICE by compiler (VGPR pinned
// at 52, loads sunk; ~3 KB/wave in flight -> 2.9 TB/s effective read).
// THIS VERSION: global_load_lds dwordx4 DMA stages the full 32 KB feature
// tile to LDS with NO dest registers -> all 32 KB/block in flight; 2
// blocks/CU = 64 KB/CU >> ~11 KB Little's-law for full HBM BW. Scatter
// reads features from LDS (ds_read_b128, conflict-free), float2 RMW as r8.
// EXECUTION CHECK: LDS_Block_Size must read 71680. FALLBACK (pre-committed):
// if LDS=71680 and still ~44 us -> genuine memory wall; k_sums DONE, pivot
// to k_dots.
//
// Block = (b, channel c); 4096 blocks x 256 thr; LDS 71680 B -> 2 blocks/CU.
__global__ __launch_bounds__(256) void k_sums(const float* __restrict__ fS,
                                              const float* __restrict__ fT,
                                              const int* __restrict__ labels,
                                              float* __restrict__ sumsS,
                                              float* __restrict__ sumsT) {
    __shared__ float2 acc[NCLS * 256];   // 38912 B
    __shared__ float  sA[NHW];           // 16384 B  (fS tile, linear)
    __shared__ float  sB[NHW];           // 16384 B  (fT tile, linear)
    const int t   = threadIdx.x;
    const int w   = t >> 6, lane = t & 63;
    const int blk = blockIdx.x;          // 0..4095
    const int b   = blk >> 9;            // 512 channels per batch
    const int c   = blk & (NC - 1);

    // Issue ALL staging DMA first: wave w stages quarter [w*1024, w*1024+1024)
    // of each tensor as 4x 1KB instructions (lds base wave-uniform; global
    // src per-lane: +lane*4 floats = 16 B).
    const size_t fbase = ((size_t)(b * NC) + c) * NHW;
    const float* gS = fS + fbase + (w << 10) + (lane << 2);
    const float* gT = fT + fbase + (w << 10) + (lane << 2);
    float* lS = sA + (w << 10);
    float* lT = sB + (w << 10);
    #pragma unroll
    for (int j = 0; j < 4; ++j) {
        g2lds16(gS + (j << 8), lS + (j << 8));
        g2lds16(gT + (j << 8), lT + (j << 8));
    }

    // Labels into registers (L2-hot, 16 KB/batch shared by 512 blocks).
    const int4* lab4 = (const int4*)(labels + b * NHW);
    int4 lab[4];
    #pragma unroll
    for (int j = 0; j < 4; ++j) lab[j] = lab4[t + (j << 8)];

    {   // zero acc while DMA is in flight: 19*256*8B / 16B = 2432 float4
        float4* av = (float4*)acc;
        const float4 z = make_float4(0.f, 0.f, 0.f, 0.f);
        for (int i = t; i < NCLS * 128; i += 256) av[i] = z;
    }
    __syncthreads();                     // drains vmcnt(0): DMA complete

    float2* a0 = acc + t;                // element k at a0[k<<8]

    #pragma unroll
    for (int i = 0; i < 4; ++i) {        // pixels 4t+1024i .. +3
        const float4 s = *(const float4*)(sA + (t << 2) + (i << 10));
        const float4 u = *(const float4*)(sB + (t << 2) + (i << 10));
        const int4   l = lab[i];
        if ((unsigned)l.x < NCLS) { float2 v = a0[l.x << 8]; v.x += s.x; v.y += u.x; a0[l.x << 8] = v; }
        if ((unsigned)l.y < NCLS) { float2 v = a0[l.y << 8]; v.x += s.y; v.y += u.y; a0[l.y << 8] = v; }
        if ((unsigned)l.z < NCLS) { float2 v = a0[l.z << 8]; v.x += s.z; v.y += u.z; a0[l.z << 8] = v; }
        if ((unsigned)l.w < NCLS) { float2 v = a0[l.w << 8]; v.x += s.w; v.y += u.w; a0[l.w << 8] = v; }
    }
    __syncthreads();

    // Reduce 19 float2-rows of 256; rows round-robin over the 4 waves.
    for (int r = w; r < NCLS; r += 4) {
        const float2* row = acc + r * 256;
        const float2 p0 = row[lane], p1 = row[lane + 64];
        const float2 p2 = row[lane + 128], p3 = row[lane + 192];
        float sx = (p0.x + p1.x) + (p2.x + p3.x);
        float sy = (p0.y + p1.y) + (p2.y + p3.y);
        sx = wave64_sum(sx);
        sy = wave64_sum(sy);
        if (lane == 63) {
            sumsS[((size_t)(b * NCLS + r)) * NC + c] = sx;
            sumsT[((size_t)(b * NCLS + r)) * NC + c] = sy;
        }
    }
}

// ---------------------------------------------------------------------------
// Kernel 3: means = sums/(count+eps) in place + per-(b,k) center norms.
// Sums the 8 count partials (deterministic). Also zeroes d_out (stream-
// ordered before k_dots' atomicAdds).
__global__ __launch_bounds__(64) void k_means(float* __restrict__ sumsS,
                                              float* __restrict__ sumsT,
                                              const float* __restrict__ countsP,
                                              float* __restrict__ normS,
                                              float* __restrict__ normT,
                                              float* __restrict__ out) {
    const int bk = blockIdx.x;           // (b,k): b = bk/NCLS
    const int t = threadIdx.x;
    if (bk == 0 && t == 0) *out = 0.f;
    const int b = bk / NCLS, k = bk - b * NCLS;
    float cnt = 0.f;
    #pragma unroll
    for (int p = 0; p < LBLK; ++p) cnt += countsP[(size_t)(b * LBLK + p) * NCLS + k];
    const float inv = 1.f / (cnt + EPSM);
    float* rS = sumsS + (size_t)bk * NC;
    float* rT = sumsT + (size_t)bk * NC;
    float aS = 0.f, aT = 0.f;
    #pragma unroll
    for (int i = 0; i < NC / 64; ++i) {
        float mS = rS[t + i * 64] * inv; rS[t + i * 64] = mS; aS += mS * mS;
        float mT = rT[t + i * 64] * inv; rT[t + i * 64] = mT; aT += mT * mT;
    }
    aS = wave64_sum(aS);
    aT = wave64_sum(aT);
    if (t == 63) { normS[bk] = sqrtf(aS); normT[bk] = sqrtf(aT); }
}

// ---------------------------------------------------------------------------
// Kernel 4 (fused k_dots + k_final, r12 version unchanged): per-pixel
// dot/norm over all 512 channels in one block, cosine + MSE inline, one
// atomicAdd per block. Wave w owns channels [128w,128w+128) in 2 rounds.
__global__ __launch_bounds__(256) void k_dots(const float* __restrict__ fS,
                                              const float* __restrict__ fT,
                                              const float* __restrict__ meansS,
                                              const float* __restrict__ meansT,
                                              const int* __restrict__ labels,
                                              const float* __restrict__ normS,
                                              const float* __restrict__ normT,
                                              float* __restrict__ out) {
    __shared__ float2 mST[4 * NCLS * 65];   // [w][k][ci] (.x=S,.y=T)
    __shared__ float4 red[4 * 64];          // [w][px]: dS,nS,dT,nT
    const int t    = threadIdx.x;
    const int w    = t >> 6, px = t & 63;
    const int blk  = blockIdx.x;            // 0..511
    const int b    = blk >> 6;              // 64 tiles per batch
    const int tile = blk & 63;
    const int n    = tile * 64 + px;

    const int l  = labels[b * NHW + n];
    const int lc = (l >= 0 && l < NCLS) ? l : 0;

    float dS = 0.f, nS = 0.f, dT = 0.f, nT = 0.f;
    #pragma unroll
    for (int r = 0; r < 2; ++r) {
        __syncthreads();                    // protect prior round's reads
        for (int i = t; i < 4 * NCLS * 64; i += 256) {
            const int ww  = i / (NCLS * 64);
            const int rem = i - ww * (NCLS * 64);
            const int k   = rem >> 6, ci = rem & 63;
            const int c   = ww * 128 + r * 64 + ci;
            mST[(ww * NCLS + k) * 65 + ci] = make_float2(
                meansS[((size_t)(b * NCLS + k)) * NC + c],
                meansT[((size_t)(b * NCLS + k)) * NC + c]);
        }
        __syncthreads();
        const size_t base = ((size_t)(b * NC) + w * 128 + r * 64) * NHW + tile * 64 + px;
        const float* pS = fS + base;
        const float* pT = fT + base;
        const float2* m0 = mST + (w * NCLS + lc) * 65;
        #pragma unroll 8
        for (int ci = 0; ci < 64; ++ci) {
            const float vS = pS[(size_t)ci * NHW];
            const float vT = pT[(size_t)ci * NHW];
            const float2 m = m0[ci];
            dS += vS * m.x; nS += vS * vS;
            dT += vT * m.y; nT += vT * vT;
        }
    }
    red[w * 64 + px] = make_float4(dS, nS, dT, nT);
    __syncthreads();

    if (w == 0) {
        const float4 a0 = red[px],       a1 = red[64 + px];
        const float4 a2 = red[128 + px], a3 = red[192 + px];
        const float DS = (a0.x + a1.x) + (a2.x + a3.x);
        const float NS = (a0.y + a1.y) + (a2.y + a3.y);
        const float DT = (a0.z + a1.z) + (a2.z + a3.z);
        const float NT = (a0.w + a1.w) + (a2.w + a3.w);
        float val = 0.f;
        if (l >= 0 && l < NCLS) {
            const float cS = DS / (fmaxf(sqrtf(NS), EPSC) * fmaxf(normS[b * NCLS + l], EPSC));
            const float cT = DT / (fmaxf(sqrtf(NT), EPSC) * fmaxf(normT[b * NCLS + l], EPSC));
            const float d = cS - cT;
            val = d * d;
        }
        val = wave64_sum(val);
        if (px == 63) atomicAdd(out, val * (1.f / (NB * NHW)));
    }
}

// ---------------------------------------------------------------------------
extern "C" void kernel_launch(void* const* d_in, const int* in_sizes, int n_in,
                              void* d_out, int out_size, void* d_ws, size_t ws_size,
                              hipStream_t stream) {
    (void)in_sizes; (void)n_in; (void)out_size; (void)ws_size;
    const float* fS     = (const float*)d_in[0];
    const float* fT     = (const float*)d_in[1];
    const int*   target = (const int*)d_in[2];

    char* ws = (char*)d_ws;
    int*   labels  = (int*)  (ws + OFF_LABELS);
    float* sumsS   = (float*)(ws + OFF_SUMS_S);   // means after k_means (in place)
    float* sumsT   = (float*)(ws + OFF_SUMS_T);
    float* normS   = (float*)(ws + OFF_NORM_S);
    float* normT   = (float*)(ws + OFF_NORM_T);
    float* countsP = (float*)(ws + OFF_COUNTSP);

    // 4 dispatches; no memsets (countsP race-free partials, d_out zeroed in k_means).
    k_labels<<<NB * LBLK, 256, 0, stream>>>(target, labels, countsP);
    k_sums  <<<NB * NC, 256, 0, stream>>>(fS, fT, labels, sumsS, sumsT);
    k_means <<<NB * NCLS, 64, 0, stream>>>(sumsS, sumsT, countsP, normS, normT,
                                           (float*)d_out);
    k_dots  <<<NB * 64, 256, 0, stream>>>(fS, fT, sumsS, sumsT, labels,
                                          normS, normT, (float*)d_out);
}